// Round 1
// 430.042 us; speedup vs baseline: 1.1111x; 1.1111x over previous
//
#include <hip/hip_runtime.h>

#define MAXV 127.0f
#define Mdim 8192
#define Ndim 4096
#define Kdim 4096

// ---- elementwise geometry (unchanged; sizes divide exactly) ----
#define EW_GRID 2048
#define EW_BLOCK 256
#define EW_STRIDE (EW_GRID * EW_BLOCK)

typedef __attribute__((ext_vector_type(4))) int int32x4;

__device__ __forceinline__ void async_load16(const void* g, void* l) {
  __builtin_amdgcn_global_load_lds(
      (const __attribute__((address_space(1))) unsigned int*)g,
      (__attribute__((address_space(3))) unsigned int*)l, 16, 0, 0);
}

__device__ __forceinline__ float amax4(float4 v) {
  return fmaxf(fmaxf(fabsf(v.x), fabsf(v.y)), fmaxf(fabsf(v.z), fabsf(v.w)));
}

__global__ __launch_bounds__(EW_BLOCK) void amax_both_kernel(
    const float4* __restrict__ x, const float4* __restrict__ w,
    int* __restrict__ out_bits) {
  const int t = blockIdx.x * EW_BLOCK + threadIdx.x;
  float mx = 0.0f, mw = 0.0f;
#pragma unroll
  for (int i = 0; i < 4; i++) {
    float4 a = x[t + (4 * i + 0) * EW_STRIDE];
    float4 b = x[t + (4 * i + 1) * EW_STRIDE];
    float4 c = x[t + (4 * i + 2) * EW_STRIDE];
    float4 d = x[t + (4 * i + 3) * EW_STRIDE];
    mx = fmaxf(mx, fmaxf(fmaxf(amax4(a), amax4(b)), fmaxf(amax4(c), amax4(d))));
  }
#pragma unroll
  for (int i = 0; i < 2; i++) {
    float4 a = w[t + (4 * i + 0) * EW_STRIDE];
    float4 b = w[t + (4 * i + 1) * EW_STRIDE];
    float4 c = w[t + (4 * i + 2) * EW_STRIDE];
    float4 d = w[t + (4 * i + 3) * EW_STRIDE];
    mw = fmaxf(mw, fmaxf(fmaxf(amax4(a), amax4(b)), fmaxf(amax4(c), amax4(d))));
  }
  for (int off = 32; off > 0; off >>= 1) {
    mx = fmaxf(mx, __shfl_down(mx, off));
    mw = fmaxf(mw, __shfl_down(mw, off));
  }
  __shared__ float sm[8];
  if ((threadIdx.x & 63) == 0) {
    sm[threadIdx.x >> 6] = mx;
    sm[4 + (threadIdx.x >> 6)] = mw;
  }
  __syncthreads();
  if (threadIdx.x == 0) {
    atomicMax(out_bits,
              __float_as_int(fmaxf(fmaxf(sm[0], sm[1]), fmaxf(sm[2], sm[3]))));
    atomicMax(out_bits + 1,
              __float_as_int(fmaxf(fmaxf(sm[4], sm[5]), fmaxf(sm[6], sm[7]))));
  }
}

__device__ __forceinline__ char4 quant4(float4 v, float s) {
  char4 q;
  q.x = (signed char)(int)fminf(fmaxf(rintf(v.x * s), -MAXV), MAXV);
  q.y = (signed char)(int)fminf(fmaxf(rintf(v.y * s), -MAXV), MAXV);
  q.z = (signed char)(int)fminf(fmaxf(rintf(v.z * s), -MAXV), MAXV);
  q.w = (signed char)(int)fminf(fmaxf(rintf(v.w * s), -MAXV), MAXV);
  return q;
}

__global__ __launch_bounds__(EW_BLOCK) void quant_both_kernel(
    const float4* __restrict__ x, const float4* __restrict__ w,
    const int* __restrict__ amax_bits, char4* __restrict__ qx,
    char4* __restrict__ qw) {
  const float sx = MAXV / __int_as_float(amax_bits[0]);
  const float sw = MAXV / __int_as_float(amax_bits[1]);
  const int t = blockIdx.x * EW_BLOCK + threadIdx.x;
#pragma unroll
  for (int i = 0; i < 4; i++) {
    int i0 = t + (4 * i + 0) * EW_STRIDE, i1 = t + (4 * i + 1) * EW_STRIDE;
    int i2 = t + (4 * i + 2) * EW_STRIDE, i3 = t + (4 * i + 3) * EW_STRIDE;
    float4 a = x[i0], b = x[i1], c = x[i2], d = x[i3];
    qx[i0] = quant4(a, sx);
    qx[i1] = quant4(b, sx);
    qx[i2] = quant4(c, sx);
    qx[i3] = quant4(d, sx);
  }
#pragma unroll
  for (int i = 0; i < 2; i++) {
    int i0 = t + (4 * i + 0) * EW_STRIDE, i1 = t + (4 * i + 1) * EW_STRIDE;
    int i2 = t + (4 * i + 2) * EW_STRIDE, i3 = t + (4 * i + 3) * EW_STRIDE;
    float4 a = w[i0], b = w[i1], c = w[i2], d = w[i3];
    qw[i0] = quant4(a, sw);
    qw[i1] = quant4(b, sw);
    qw[i2] = quant4(c, sw);
    qw[i3] = quant4(d, sw);
  }
}

// ---------------------------------------------------------------------------
// 256x256 8-phase i8 GEMM (T2 swizzle + T3/T4 counted vmcnt + T5 setprio).
// C[m][n] = sum_k Aq[m][k]*Bq[n][k], both K-contiguous. 8 waves (2Mx4N),
// BK = 128 i8 (128 B rows), MFMA i32_16x16x64_i8, per-wave 128x64 output.
// LDS 128 KiB: [buf 0/1][A0,A1,B0,B1] halves of 128 rows x 128 B.
// Per phase: ds_reads + 1 half-tile stage (2x global_load_lds dwordx4) +
// barrier + lgkmcnt(0) + 16 MFMA + barrier. vmcnt(4) only at phases 3/7.
// Swizzle: col ^= (row&7)<<4, applied on pre-swizzled global src + ds_read.
// ---------------------------------------------------------------------------
#define BM 256
#define BN 256
#define BKB 128
#define HALF 16384
#define NIT 15  // main iterations; last iteration (tiles 30,31) is peeled

#define LDSA(buf) (lds + ((buf) * 4 + wm) * HALF)
#define LDSB(buf) (lds + ((buf) * 4 + 2 + (wn >> 1)) * HALF)

#define STG_A(buf, h, kt)                                          \
  {                                                                \
    signed char* d = lds + ((buf) * 4 + (h)) * HALF + wdst;        \
    const signed char* s = aS + (h) * HSK + (size_t)(kt) * BKB;    \
    async_load16(s, d);                                            \
    async_load16(s + 64 * (size_t)Kdim, d + 8192);                 \
  }
#define STG_B(buf, h, kt)                                          \
  {                                                                \
    signed char* d = lds + ((buf) * 4 + 2 + (h)) * HALF + wdst;    \
    const signed char* s = bS + (h) * HSK + (size_t)(kt) * BKB;    \
    async_load16(s, d);                                            \
    async_load16(s + 64 * (size_t)Kdim, d + 8192);                 \
  }

#define LOAD_A(buf, mh)                                            \
  {                                                                \
    const signed char* ab = LDSA(buf) + (mh) * 8192;               \
    _Pragma("unroll") for (int mi = 0; mi < 4; mi++) {             \
      afr[mi][0] = *(const int32x4*)(ab + mi * 2048 + aoff0);      \
      afr[mi][1] = *(const int32x4*)(ab + mi * 2048 + aoff1);      \
    }                                                              \
  }
#define LOAD_B(buf, g)                                             \
  {                                                                \
    const signed char* bb = LDSB(buf) + brow0 + (g) * 4096;        \
    _Pragma("unroll") for (int j = 0; j < 2; j++) {                \
      bfr[(g) * 2 + j][0] = *(const int32x4*)(bb + j * 2048 + aoff0); \
      bfr[(g) * 2 + j][1] = *(const int32x4*)(bb + j * 2048 + aoff1); \
    }                                                              \
  }

#define MFMA_Q(ma, nb)                                                        \
  _Pragma("unroll") for (int mi = 0; mi < 4; mi++)                            \
  _Pragma("unroll") for (int nj = 0; nj < 2; nj++)                            \
  _Pragma("unroll") for (int ks = 0; ks < 2; ks++)                            \
      acc[(ma) * 4 + mi][(nb) * 2 + nj] =                                     \
          __builtin_amdgcn_mfma_i32_16x16x64_i8(                              \
              afr[mi][ks], bfr[(nb) * 2 + nj][ks],                            \
              acc[(ma) * 4 + mi][(nb) * 2 + nj], 0, 0, 0);

#define SYNC_MID()                                       \
  __builtin_amdgcn_s_barrier();                          \
  asm volatile("s_waitcnt lgkmcnt(0)" ::: "memory");     \
  __builtin_amdgcn_sched_barrier(0);                     \
  __builtin_amdgcn_s_setprio(1);

#define PH_END()                \
  __builtin_amdgcn_s_setprio(0); \
  __builtin_amdgcn_s_barrier();

#define PH_END_V(n)                                      \
  __builtin_amdgcn_s_setprio(0);                         \
  asm volatile("s_waitcnt vmcnt(" #n ")" ::: "memory");  \
  __builtin_amdgcn_s_barrier();

__global__ __launch_bounds__(512, 2) void gemm_i8_kernel(
    const signed char* __restrict__ Aq, const signed char* __restrict__ Bq,
    const float* __restrict__ bias, const int* __restrict__ amax_bits,
    float* __restrict__ out) {
  __shared__ signed char lds[8 * HALF];  // 128 KiB

  const int tid = threadIdx.x;
  const int lane = tid & 63;
  const int w = tid >> 6;
  const int wm = w >> 2;  // 0..1
  const int wn = w & 3;   // 0..3

  const int m0 = blockIdx.y * BM;
  const int n0 = blockIdx.x * BN;

  // staging: thread covers rows r0 and r0+64 of a half, same (swizzled) col
  const int r0 = tid >> 3;
  const int gcol = ((tid & 7) * 16) ^ ((r0 & 7) << 4);
  const signed char* aS = Aq + (size_t)(m0 + r0) * Kdim + gcol;
  const signed char* bS = Bq + (size_t)(n0 + r0) * Kdim + gcol;
  const size_t HSK = (size_t)128 * Kdim;
  const int wdst = w * 1024;  // wave-uniform LDS dest

  // ds-read offsets (row = lane&15 within frag; swizzle uses lane&7)
  const int aoff0 =
      (lane & 15) * 128 + (((lane >> 4) * 16) ^ ((lane & 7) << 4));
  const int aoff1 =
      (lane & 15) * 128 + ((64 + (lane >> 4) * 16) ^ ((lane & 7) << 4));
  const int brow0 = (wn & 1) * 8192;

  int32x4 acc[8][4] = {};
  int32x4 afr[4][2], bfr[4][2];

  // prologue: tile0 -> buf0 (all halves); tile1 B-halves -> buf1
  STG_A(0, 0, 0);
  STG_A(0, 1, 0);
  STG_B(0, 0, 0);
  STG_B(0, 1, 0);
  STG_B(1, 0, 1);
  STG_B(1, 1, 1);
  asm volatile("s_waitcnt vmcnt(4)" ::: "memory");
  __builtin_amdgcn_s_barrier();

#pragma unroll 1
  for (int it = 0; it < NIT; ++it) {
    const int kt1 = 2 * it + 1, kt2 = 2 * it + 2, kt3 = 2 * it + 3;
    // phase 0: tile 2i quadrant (0,0)
    LOAD_A(0, 0); LOAD_B(0, 0); STG_A(1, 0, kt1);
    SYNC_MID(); MFMA_Q(0, 0); PH_END();
    // phase 1
    LOAD_B(0, 1); STG_A(1, 1, kt1);
    SYNC_MID(); MFMA_Q(0, 1); PH_END();
    // phase 2
    LOAD_A(0, 1); STG_B(0, 0, kt2);
    SYNC_MID(); MFMA_Q(1, 1); PH_END();
    // phase 3 (counted wait: covers tile 2i+1 A/B for phase 4)
    STG_B(0, 1, kt2);
    SYNC_MID(); MFMA_Q(1, 0); PH_END_V(4);
    // phase 4: tile 2i+1 quadrant (0,0)
    LOAD_A(1, 0); LOAD_B(1, 0); STG_A(0, 0, kt2);
    SYNC_MID(); MFMA_Q(0, 0); PH_END();
    // phase 5
    LOAD_B(1, 1); STG_A(0, 1, kt2);
    SYNC_MID(); MFMA_Q(0, 1); PH_END();
    // phase 6
    LOAD_A(1, 1); STG_B(1, 0, kt3);
    SYNC_MID(); MFMA_Q(1, 1); PH_END();
    // phase 7 (counted wait: covers tile 2i+2 for next iter phase 0)
    STG_B(1, 1, kt3);
    SYNC_MID(); MFMA_Q(1, 0); PH_END_V(4);
  }

  // peeled last iteration: tiles 30 (buf0) / 31 (buf1); only stage 31's A
  {
    LOAD_A(0, 0); LOAD_B(0, 0); STG_A(1, 0, 31);
    SYNC_MID(); MFMA_Q(0, 0); PH_END();
    LOAD_B(0, 1); STG_A(1, 1, 31);
    SYNC_MID(); MFMA_Q(0, 1); PH_END();
    LOAD_A(0, 1);
    SYNC_MID(); MFMA_Q(1, 1); PH_END();
    SYNC_MID(); MFMA_Q(1, 0); PH_END_V(0);  // full drain: no DMA in flight
    LOAD_A(1, 0); LOAD_B(1, 0);
    SYNC_MID(); MFMA_Q(0, 0); PH_END();
    LOAD_B(1, 1);
    SYNC_MID(); MFMA_Q(0, 1); PH_END();
    LOAD_A(1, 1);
    SYNC_MID(); MFMA_Q(1, 1); PH_END();
    SYNC_MID(); MFMA_Q(1, 0);
    __builtin_amdgcn_s_setprio(0);
  }

  // epilogue: dequant + bias, scalar stores coalesced across lanes
  const float sx = MAXV / __int_as_float(amax_bits[0]);
  const float sw = MAXV / __int_as_float(amax_bits[1]);
  const float inv = 1.0f / (sx * sw);
  const int crow = (lane >> 4) * 4;
  const int ccol = lane & 15;
#pragma unroll
  for (int nj = 0; nj < 4; nj++) {
    const int n = n0 + wn * 64 + nj * 16 + ccol;
    const float bv = bias[n];
#pragma unroll
    for (int a = 0; a < 8; a++) {
      const int m = m0 + wm * 128 + a * 16 + crow;
      float* op = out + (size_t)m * Ndim + n;
#pragma unroll
      for (int r = 0; r < 4; r++)
        op[(size_t)r * Ndim] = (float)acc[a][nj][r] * inv + bv;
    }
  }
}

extern "C" void kernel_launch(void* const* d_in, const int* in_sizes, int n_in,
                              void* d_out, int out_size, void* d_ws,
                              size_t ws_size, hipStream_t stream) {
  const float* x = (const float*)d_in[0];
  const float* wgt = (const float*)d_in[1];
  const float* bias = (const float*)d_in[2];
  float* out = (float*)d_out;

  int* amax = (int*)d_ws;
  signed char* qx = (signed char*)d_ws + 256;
  signed char* qw = qx + (size_t)Mdim * Kdim;

  hipMemsetAsync(amax, 0, 2 * sizeof(int), stream);
  hipLaunchKernelGGL(amax_both_kernel, dim3(EW_GRID), dim3(EW_BLOCK), 0, stream,
                     (const float4*)x, (const float4*)wgt, amax);
  hipLaunchKernelGGL(quant_both_kernel, dim3(EW_GRID), dim3(EW_BLOCK), 0,
                     stream, (const float4*)x, (const float4*)wgt, amax,
                     (char4*)qx, (char4*)qw);
  hipLaunchKernelGGL(gemm_i8_kernel, dim3(Ndim / BN, Mdim / BM), dim3(512), 0,
                     stream, qx, qw, bias, amax, out);
}